// Round 7
// baseline (372.127 us; speedup 1.0000x reference)
//
#include <hip/hip_runtime.h>
#include <stdint.h>

#define B_ 8
#define C_ 256
#define N_ 4096
#define CQK 32

typedef __attribute__((ext_vector_type(8))) _Float16 f16x8;
typedef __attribute__((ext_vector_type(2))) _Float16 f16x2;
typedef __attribute__((ext_vector_type(4))) float f32x4;

#define LOG2E 1.4426950408889634f

// ---------------------------------------------------------------------------
// Kernel 1: transpose x [b][c][n] fp32 -> xT [b][n][c] fp16 (c contiguous).
// xT lives in d_out[0:16.78MB]; dead after proj_gemm (attn then overwrites
// d_out with y). Proven pattern (r2/r5/r6).
// ---------------------------------------------------------------------------
__global__ __launch_bounds__(256) void xpose_kernel(
    const float* __restrict__ x, _Float16* __restrict__ xT)
{
  __shared__ float xs[64 * 129];
  const int t  = threadIdx.x;
  const int blk = blockIdx.x;
  const int nt = blk & 31;          // n-tile (128 px)
  const int ct = (blk >> 5) & 3;    // c-tile (64 ch)
  const int b  = blk >> 7;
  const int c0 = ct * 64, n0 = nt * 128;

  #pragma unroll
  for (int p = 0; p < 8; ++p) {
    int cc = p * 8 + (t >> 5);
    int nn = (t & 31) * 4;
    float4 v = *(const float4*)(x + ((size_t)(b * C_ + c0 + cc)) * N_ + n0 + nn);
    xs[cc * 129 + nn]     = v.x;
    xs[cc * 129 + nn + 1] = v.y;
    xs[cc * 129 + nn + 2] = v.z;
    xs[cc * 129 + nn + 3] = v.w;
  }
  __syncthreads();
  #pragma unroll
  for (int p = 0; p < 4; ++p) {
    int id = p * 256 + t;
    int cchunk = id & 7, n = id >> 3;
    _Float16 h[8];
    #pragma unroll
    for (int j = 0; j < 8; ++j) h[j] = (_Float16)xs[(cchunk * 8 + j) * 129 + n];
    *(f16x8*)(xT + ((size_t)(b * N_) + n0 + n) * C_ + c0 + cchunk * 8) = *(f16x8*)h;
  }
}

// ---------------------------------------------------------------------------
// Kernel 2: weights -> fp16 Wcat[320][256] (0-31 wq, 32-63 wk, 64-319 wv).
// ---------------------------------------------------------------------------
__global__ __launch_bounds__(256) void wconv_kernel(
    const float* __restrict__ wq, const float* __restrict__ wk,
    const float* __restrict__ wv, _Float16* __restrict__ wf)
{
  int idx = blockIdx.x * 256 + threadIdx.x;
  int e = idx * 4;
  int o = e >> 8, c = e & 255;
  const float* src;
  if (o < 32)      src = wq + o * 256 + c;
  else if (o < 64) src = wk + (o - 32) * 256 + c;
  else             src = wv + (o - 64) * 256 + c;
  float4 v = *(const float4*)src;
  _Float16 h[4] = {(_Float16)v.x, (_Float16)v.y, (_Float16)v.z, (_Float16)v.w};
  *(uint2*)(wf + e) = *(uint2*)h;
}

// ---------------------------------------------------------------------------
// Kernel 3: projection GEMM (fp16 MFMA). q stored pre-scaled by log2(e).
// Outputs (qf, kf, vfp) in d_ws.
// ---------------------------------------------------------------------------
__global__ __launch_bounds__(256, 4) void proj_gemm_kernel(
    const _Float16* __restrict__ xT, const _Float16* __restrict__ wf,
    const float* __restrict__ bq, const float* __restrict__ bk,
    const float* __restrict__ bv,
    _Float16* __restrict__ qf, _Float16* __restrict__ kf,
    _Float16* __restrict__ vout)
{
  const int t = threadIdx.x, lane = t & 63;
  const int w = t >> 6;
  const int l15 = lane & 15, q4 = lane >> 4;
  const int blk = blockIdx.x;
  const int otile = blk % 5;          // 0 = q/k, 1..4 = v
  const int nt = blk / 5;
  const int b  = nt >> 5;
  const int n0 = (nt & 31) * 128;
  const int o0w = (w & 1) * 32;
  const int n0w = (w >> 1) * 64;

  f32x4 acc[2][4];
  const f32x4 zf = {0.f, 0.f, 0.f, 0.f};
  #pragma unroll
  for (int a = 0; a < 2; ++a)
    #pragma unroll
    for (int bb = 0; bb < 4; ++bb) acc[a][bb] = zf;

  const _Float16* wbase = wf + (size_t)(otile * 64 + o0w) * 256;
  const _Float16* xbase = xT + ((size_t)(b * N_) + n0 + n0w) * C_;

  #pragma unroll
  for (int kc = 0; kc < 8; ++kc) {
    f16x8 af[2], bfr[4];
    #pragma unroll
    for (int ob = 0; ob < 2; ++ob)
      af[ob] = *(const f16x8*)(wbase + (ob * 16 + l15) * 256 + kc * 32 + q4 * 8);
    #pragma unroll
    for (int nb = 0; nb < 4; ++nb)
      bfr[nb] = *(const f16x8*)(xbase + (nb * 16 + l15) * 256 + kc * 32 + q4 * 8);
    #pragma unroll
    for (int ob = 0; ob < 2; ++ob)
      #pragma unroll
      for (int nb = 0; nb < 4; ++nb)
        acc[ob][nb] = __builtin_amdgcn_mfma_f32_16x16x32_f16(af[ob], bfr[nb], acc[ob][nb], 0, 0, 0);
  }

  if (otile == 0) {
    _Float16* dst = (o0w == 0) ? qf : kf;
    const float* bias = (o0w == 0) ? bq : bk;
    const float scl = (o0w == 0) ? LOG2E : 1.0f;   // fold log2(e) into q
    #pragma unroll
    for (int ob = 0; ob < 2; ++ob) {
      float4 b4 = *(const float4*)(bias + ob * 16 + q4 * 4);
      #pragma unroll
      for (int nb = 0; nb < 4; ++nb) {
        int pixel = n0 + n0w + nb * 16 + l15;
        _Float16 h[4];
        h[0] = (_Float16)((acc[ob][nb][0] + b4.x) * scl);
        h[1] = (_Float16)((acc[ob][nb][1] + b4.y) * scl);
        h[2] = (_Float16)((acc[ob][nb][2] + b4.z) * scl);
        h[3] = (_Float16)((acc[ob][nb][3] + b4.w) * scl);
        *(uint2*)(dst + ((size_t)(b * N_) + pixel) * CQK + ob * 16 + q4 * 4) = *(uint2*)h;
      }
    }
  } else {
    int cbase = (otile - 1) * 64 + o0w;
    #pragma unroll
    for (int ob = 0; ob < 2; ++ob) {
      float4 b4 = *(const float4*)(bv + cbase + ob * 16 + q4 * 4);
      #pragma unroll
      for (int nb = 0; nb < 4; ++nb) {
        int pixel = n0 + n0w + nb * 16 + l15;
        #pragma unroll
        for (int r = 0; r < 4; ++r) {
          int c = cbase + ob * 16 + q4 * 4 + r;
          float bval = (r == 0) ? b4.x : (r == 1) ? b4.y : (r == 2) ? b4.z : b4.w;
          vout[((size_t)(b * C_) + c) * N_ + pixel] = (_Float16)(acc[ob][nb][r] + bval);
        }
      }
    }
  }
}

// ---------------------------------------------------------------------------
// Kernel 4: flash attention + residual.
// 256 thr (4 waves), M=64 q/block, CHANNEL-SPLIT x2: block owns 128 channels.
// Grid 1024 = 4 blocks/CU (16 waves/CU). b = blk&7 -> XCD-local K/V.
// S-phase per wave: 16 complete query rows, in-wave softmax (validated).
// PV: wave = c-strip of 32 x all 64 i; V double-buffered in REGISTERS
// (prefetched one iter ahead -> no VMEM stall after the barrier).
// One barrier/iter (P+alpha ping-pong). LDS-transposed coalesced epilogue.
// ---------------------------------------------------------------------------
__global__ __launch_bounds__(256, 4) void attn_kernel(
    const float* __restrict__ x, const float* __restrict__ gptr,
    const _Float16* __restrict__ qf, const _Float16* __restrict__ kf,
    const _Float16* __restrict__ vf, float* __restrict__ yout)
{
  // LDS map:
  //   [0, 18432)      P ping-pong: 2 x (64 rows x 144 B)          (loop)
  //   [0, 34816)      epilogue transpose: 4 waves x 32 x 68 f32   (epilogue)
  //   [34816, 35328)  alpha ping-pong 2 x 64 f32
  //   [35328, 35584)  lrow 64 f32
  __shared__ __align__(16) char smem[35584];
  float* alph  = (float*)(smem + 34816);
  float* lrowl = (float*)(smem + 35328);

  const int t = threadIdx.x, lane = t & 63;
  const int w = t >> 6;                  // 4 waves
  const int l15 = lane & 15, q4 = lane >> 4;
  const int b  = blockIdx.x & 7;
  const int cs = (blockIdx.x >> 3) & 1;
  const int i0 = (blockIdx.x >> 4) * 64;
  const int c0 = cs * 128;
  const int myrow = w * 16;              // wave's 16 query rows (S phase)

  // Q B-frag: lane -> i = l15 (wave's rows), k = q4*8+j
  const f16x8 qfr = *(const f16x8*)(qf + ((size_t)(b * N_) + i0 + myrow + l15) * CQK + q4 * 8);

  const _Float16* kb = kf + (size_t)b * N_ * CQK;
  const _Float16* vb = vf + ((size_t)(b * C_) + c0 + w * 32) * N_;  // wave's 32-ch V base

  // PV acc: c = c0 + w*32 + ct*16 + q4*4 + r, i = ib*16 + l15
  f32x4 acc[2][4];
  const f32x4 zf = {0.f, 0.f, 0.f, 0.f};
  #pragma unroll
  for (int a = 0; a < 2; ++a)
    #pragma unroll
    for (int bb = 0; bb < 4; ++bb) acc[a][bb] = zf;

  float mold = -1e30f, lrun = 0.f;

  // K frags (A-operand: l15 = j, q4*8+r = c'); V frags (A-op: l15 = c-row)
  f16x8 kcur[4], vA[4], vB[4];
  #pragma unroll
  for (int jb = 0; jb < 4; ++jb)
    kcur[jb] = *(const f16x8*)(kb + (size_t)(jb * 16 + l15) * CQK + q4 * 8);
  #pragma unroll
  for (int ks = 0; ks < 2; ++ks)
    #pragma unroll
    for (int ct = 0; ct < 2; ++ct)
      vA[ks * 2 + ct] = *(const f16x8*)(vb + (size_t)(ct * 16 + l15) * N_ + ks * 32 + q4 * 8);

  auto body = [&](int jt, f16x8* vcur, f16x8* vnxt) {
    const int jbase = jt * 64;
    const int pp = jt & 1;
    char* Pcur = smem + pp * 9216;
    float* acur = alph + pp * 64;

    // ---- S: wave's 16 rows x 64 j ----
    f32x4 sv[4];
    #pragma unroll
    for (int jb = 0; jb < 4; ++jb)
      sv[jb] = __builtin_amdgcn_mfma_f32_16x16x32_f16(kcur[jb], qfr, zf, 0, 0, 0);

    // prefetch next K and V tiles (last iter wraps to 0: harmless)
    const int jnext = (jt == 63) ? 0 : jbase + 64;
    #pragma unroll
    for (int jb = 0; jb < 4; ++jb)
      kcur[jb] = *(const f16x8*)(kb + (size_t)(jnext + jb * 16 + l15) * CQK + q4 * 8);
    #pragma unroll
    for (int ks = 0; ks < 2; ++ks)
      #pragma unroll
      for (int ct = 0; ct < 2; ++ct)
        vnxt[ks * 2 + ct] = *(const f16x8*)(vb + (size_t)(ct * 16 + l15) * N_ + jnext + ks * 32 + q4 * 8);

    // ---- in-wave online softmax (log2 domain) ----
    float lm = fmaxf(fmaxf(fmaxf(sv[0][0], sv[0][1]), fmaxf(sv[0][2], sv[0][3])),
                     fmaxf(fmaxf(sv[1][0], sv[1][1]), fmaxf(sv[1][2], sv[1][3])));
    lm = fmaxf(lm, fmaxf(fmaxf(fmaxf(sv[2][0], sv[2][1]), fmaxf(sv[2][2], sv[2][3])),
                         fmaxf(fmaxf(sv[3][0], sv[3][1]), fmaxf(sv[3][2], sv[3][3]))));
    lm = fmaxf(lm, __shfl_xor(lm, 16));
    lm = fmaxf(lm, __shfl_xor(lm, 32));
    float mnew = fmaxf(mold, lm);
    float alpha = __builtin_amdgcn_exp2f(mold - mnew);

    float p[4][4];
    float ts = 0.f;
    #pragma unroll
    for (int jb = 0; jb < 4; ++jb)
      #pragma unroll
      for (int r = 0; r < 4; ++r) {
        float pv = __builtin_amdgcn_exp2f(sv[jb][r] - mnew);
        p[jb][r] = pv; ts += pv;
      }
    ts += __shfl_xor(ts, 16);
    ts += __shfl_xor(ts, 32);
    lrun = lrun * alpha + ts;
    mold = mnew;

    // ---- P -> LDS (row = wave's i, col j = jb*16 + q4*4 + r) + alpha ----
    #pragma unroll
    for (int jb = 0; jb < 4; ++jb) {
      uint2 pk;
      pk.x = __builtin_bit_cast(unsigned, __builtin_amdgcn_cvt_pkrtz(p[jb][0], p[jb][1]));
      pk.y = __builtin_bit_cast(unsigned, __builtin_amdgcn_cvt_pkrtz(p[jb][2], p[jb][3]));
      *(uint2*)(Pcur + (myrow + l15) * 144 + jb * 32 + q4 * 8) = pk;
    }
    if (lane < 16) acur[myrow + lane] = alpha;
    __syncthreads();                       // one barrier per iter

    // ---- PV: wave = 32 c x 64 i; V frags already in registers ----
    float av[4];
    #pragma unroll
    for (int ib = 0; ib < 4; ++ib) av[ib] = acur[ib * 16 + l15];
    #pragma unroll
    for (int ct = 0; ct < 2; ++ct)
      #pragma unroll
      for (int ib = 0; ib < 4; ++ib)
        #pragma unroll
        for (int r = 0; r < 4; ++r) acc[ct][ib][r] *= av[ib];

    #pragma unroll
    for (int ks = 0; ks < 2; ++ks) {
      f16x8 pfr[4];
      #pragma unroll
      for (int ib = 0; ib < 4; ++ib)
        pfr[ib] = *(const f16x8*)(Pcur + (ib * 16 + l15) * 144 + ks * 64 + q4 * 16);
      #pragma unroll
      for (int ct = 0; ct < 2; ++ct) {
        #pragma unroll
        for (int ib = 0; ib < 4; ++ib)
          acc[ct][ib] = __builtin_amdgcn_mfma_f32_16x16x32_f16(vcur[ks * 2 + ct], pfr[ib], acc[ct][ib], 0, 0, 0);
      }
    }
  };

  for (int jt = 0; jt < 64; jt += 2) {
    body(jt, vA, vB);
    body(jt + 1, vB, vA);
  }

  // ---- epilogue: coalesced via LDS transpose (stride-68 pad) ----
  if (lane < 16) lrowl[myrow + lane] = lrun;
  __syncthreads();   // lrowl visible + all PV reads of P done before overwrite

  float* Ew = (float*)(smem + w * 8704);   // wave-private 32 x 68 f32
  float linv[4];
  #pragma unroll
  for (int ib = 0; ib < 4; ++ib) linv[ib] = 1.0f / lrowl[ib * 16 + l15];
  #pragma unroll
  for (int ct = 0; ct < 2; ++ct)
    #pragma unroll
    for (int ib = 0; ib < 4; ++ib)
      #pragma unroll
      for (int r = 0; r < 4; ++r)
        Ew[(ct * 16 + q4 * 4 + r) * 68 + ib * 16 + l15] = acc[ct][ib][r] * linv[ib];

  const float gamma = gptr[0];
  #pragma unroll
  for (int p = 0; p < 8; ++p) {
    int g = p * 64 + lane;
    int row = g >> 4;            // 0..31 (c within wave strip)
    int col = (g & 15) * 4;      // 0..60 (i offset)
    float4 o = *(const float4*)&Ew[row * 68 + col];
    size_t off = ((size_t)(b * C_) + c0 + w * 32 + row) * N_ + i0 + col;
    float4 xr = *(const float4*)(x + off);
    float4 yv;
    yv.x = fmaf(gamma, o.x, xr.x);
    yv.y = fmaf(gamma, o.y, xr.y);
    yv.z = fmaf(gamma, o.z, xr.z);
    yv.w = fmaf(gamma, o.w, xr.w);
    *(float4*)(yout + off) = yv;
  }
}

// ---------------------------------------------------------------------------
// Kernel 5: BN statistics from fp32 y (d_out); one 1024-thr block per channel.
// ---------------------------------------------------------------------------
__global__ __launch_bounds__(1024) void bnstats_kernel(
    const float* __restrict__ y, float* __restrict__ meanw, float* __restrict__ rstdw)
{
  const int c = blockIdx.x;
  const int t = threadIdx.x;
  float s1 = 0.f, s2 = 0.f;
  #pragma unroll
  for (int b = 0; b < B_; ++b) {
    float4 v = *(const float4*)(y + ((size_t)(b * C_ + c)) * N_ + t * 4);
    s1 += v.x + v.y + v.z + v.w;
    s2 += v.x * v.x + v.y * v.y + v.z * v.z + v.w * v.w;
  }
  #pragma unroll
  for (int off = 1; off < 64; off <<= 1) {
    s1 += __shfl_xor(s1, off);
    s2 += __shfl_xor(s2, off);
  }
  __shared__ float r1[16], r2[16];
  const int wid = t >> 6;
  if ((t & 63) == 0) { r1[wid] = s1; r2[wid] = s2; }
  __syncthreads();
  if (t == 0) {
    float a1 = 0.f, a2 = 0.f;
    #pragma unroll
    for (int k = 0; k < 16; ++k) { a1 += r1[k]; a2 += r2[k]; }
    float mean = a1 * (1.0f / 32768.0f);
    float var  = a2 * (1.0f / 32768.0f) - mean * mean;
    meanw[c] = mean;
    rstdw[c] = rsqrtf(var + 1e-5f);
  }
}

// ---------------------------------------------------------------------------
// Kernel 6: BN normalize + ReLU, in-place fp32 on d_out.
// ---------------------------------------------------------------------------
__global__ __launch_bounds__(256) void bnapply_kernel(
    float* __restrict__ y,
    const float* __restrict__ meanw, const float* __restrict__ rstdw,
    const float* __restrict__ bnw, const float* __restrict__ bnb)
{
  size_t idx = (size_t)blockIdx.x * 256 + threadIdx.x;
  size_t el = idx * 8;
  int c = (int)((el >> 12) & 255);
  float sc = bnw[c] * rstdw[c];
  float sh = fmaf(-meanw[c], sc, bnb[c]);
  float4 v0 = *(const float4*)(y + el);
  float4 v1 = *(const float4*)(y + el + 4);
  v0.x = fmaxf(fmaf(v0.x, sc, sh), 0.f);
  v0.y = fmaxf(fmaf(v0.y, sc, sh), 0.f);
  v0.z = fmaxf(fmaf(v0.z, sc, sh), 0.f);
  v0.w = fmaxf(fmaf(v0.w, sc, sh), 0.f);
  v1.x = fmaxf(fmaf(v1.x, sc, sh), 0.f);
  v1.y = fmaxf(fmaf(v1.y, sc, sh), 0.f);
  v1.z = fmaxf(fmaf(v1.z, sc, sh), 0.f);
  v1.w = fmaxf(fmaf(v1.w, sc, sh), 0.f);
  *(float4*)(y + el) = v0;
  *(float4*)(y + el + 4) = v1;
}

extern "C" void kernel_launch(void* const* d_in, const int* in_sizes, int n_in,
                              void* d_out, int out_size, void* d_ws, size_t ws_size,
                              hipStream_t stream)
{
  const float* x   = (const float*)d_in[0];
  const float* wq  = (const float*)d_in[1];
  const float* bq  = (const float*)d_in[2];
  const float* wk  = (const float*)d_in[3];
  const float* bk  = (const float*)d_in[4];
  const float* wv  = (const float*)d_in[5];
  const float* bv  = (const float*)d_in[6];
  const float* gm  = (const float*)d_in[7];
  const float* bnw = (const float*)d_in[8];
  const float* bnb = (const float*)d_in[9];

  // d_out: xT fp16 [0:16.78MB] during stages 1-3, then y fp32 (33.55MB).
  _Float16* xT = (_Float16*)d_out;
  float* y = (float*)d_out;

  // ws (~22 MB): qf | kf | vfp | wf | meanw | rstdw
  char* ws = (char*)d_ws;
  _Float16* qf  = (_Float16*)(ws);
  _Float16* kf  = (_Float16*)(ws + ((size_t)2 << 20));
  _Float16* vfp = (_Float16*)(ws + ((size_t)4 << 20));
  _Float16* wf  = (_Float16*)(ws + ((size_t)21 << 20));
  float* meanw  = (float*)(ws + ((size_t)22 << 20));
  float* rstdw  = (float*)(ws + ((size_t)22 << 20) + 4096);

  hipLaunchKernelGGL(xpose_kernel, dim3(1024), dim3(256), 0, stream, x, xT);
  hipLaunchKernelGGL(wconv_kernel, dim3(80), dim3(256), 0, stream, wq, wk, wv, wf);
  hipLaunchKernelGGL(proj_gemm_kernel, dim3(1280), dim3(256), 0, stream,
                     xT, wf, bq, bk, bv, qf, kf, vfp);
  hipLaunchKernelGGL(attn_kernel, dim3(1024), dim3(256), 0, stream,
                     x, gm, qf, kf, vfp, y);
  hipLaunchKernelGGL(bnstats_kernel, dim3(256), dim3(1024), 0, stream,
                     y, meanw, rstdw);
  hipLaunchKernelGGL(bnapply_kernel, dim3(4096), dim3(256), 0, stream,
                     y, meanw, rstdw, bnw, bnb);
}